// Round 2
// baseline (447.069 us; speedup 1.0000x reference)
//
#include <hip/hip_runtime.h>
#include <cstdint>

constexpr int NCOLS   = 4096;
constexpr int THREADS = 256;
constexpr int EPT     = 16;     // elements per thread
constexpr int CAP     = 256;    // max candidates (4 per lane per wave)

__global__ __launch_bounds__(THREADS) void topk_sparsify(
    const float* __restrict__ X, float* __restrict__ out)
{
    const int row  = blockIdx.x;
    const int t    = threadIdx.x;
    const int wave = t >> 6;
    const int lane = t & 63;

    __shared__ uint32_t wsum[4];
    __shared__ float    fsum[4];
    __shared__ uint32_t cand[CAP];

    const float4* __restrict__ x4 =
        reinterpret_cast<const float4*>(X + (size_t)row * NCOLS);
    float4* __restrict__ o4 = reinterpret_cast<float4*>(out + (size_t)row * NCOLS);

    // ---- load row; keep |x| bit patterns + packed sign bits; accumulate sum(x^2)
    uint32_t a[EPT];
    uint32_t sbits = 0;
    float ss = 0.0f;
#pragma unroll
    for (int i = 0; i < 4; ++i) {
        float4 v = x4[t + THREADS * i];
        uint32_t u0 = __float_as_uint(v.x), u1 = __float_as_uint(v.y);
        uint32_t u2 = __float_as_uint(v.z), u3 = __float_as_uint(v.w);
        a[4*i+0] = u0 & 0x7FFFFFFFu;  a[4*i+1] = u1 & 0x7FFFFFFFu;
        a[4*i+2] = u2 & 0x7FFFFFFFu;  a[4*i+3] = u3 & 0x7FFFFFFFu;
        sbits |= (u0 >> 31) << (4*i+0);
        sbits |= (u1 >> 31) << (4*i+1);
        sbits |= (u2 >> 31) << (4*i+2);
        sbits |= (u3 >> 31) << (4*i+3);
        ss = fmaf(v.x, v.x, ss); ss = fmaf(v.y, v.y, ss);
        ss = fmaf(v.z, v.z, ss); ss = fmaf(v.w, v.w, ss);
    }

    // ---- sigma estimate (block reduce of sum of squares)
#pragma unroll
    for (int off = 32; off >= 1; off >>= 1) ss += __shfl_xor(ss, off, 64);
    if (lane == 0) fsum[wave] = ss;
    __syncthreads();
    const float sigma = sqrtf(fsum[0] + fsum[1] + fsum[2] + fsum[3]) * (1.0f / 64.0f);

    // ---- find threshold T with 65 <= C <= CAP (typically 1 iteration)
    float T = 2.1f * sigma;
    uint32_t tb = 0, C = 0, myc = 0;
    bool ok = false;
    for (int it = 0; it < 16; ++it) {
        tb  = __float_as_uint(T);
        myc = 0;
#pragma unroll
        for (int i = 0; i < EPT; ++i) myc += (a[i] > tb) ? 1u : 0u;
        uint32_t c = myc;
#pragma unroll
        for (int off = 32; off >= 1; off >>= 1) c += __shfl_xor(c, off, 64);
        __syncthreads();                 // protect wsum/fsum prior use
        if (lane == 0) wsum[wave] = c;
        __syncthreads();
        C = wsum[0] + wsum[1] + wsum[2] + wsum[3];
        if (C >= 65u && C <= (uint32_t)CAP) { ok = true; break; }
        T = (C < 65u) ? T * 0.70f : T * 1.35f;
    }

    uint32_t b65;
    if (ok) {
        // ---- gather candidates compactly (shuffle prefix sums, no atomics)
        uint32_t pre = myc;
#pragma unroll
        for (int off = 1; off < 64; off <<= 1) {
            uint32_t v = __shfl_up(pre, off, 64);
            if (lane >= off) pre += v;
        }
        uint32_t wtot = __shfl(pre, 63, 64);
        __syncthreads();                 // wsum reuse
        if (lane == 0) wsum[wave] = wtot;
        __syncthreads();
        uint32_t base = 0;
#pragma unroll
        for (int w = 0; w < 4; ++w) base += (w < wave) ? wsum[w] : 0u;
        uint32_t o = base + pre - myc;
#pragma unroll
        for (int i = 0; i < EPT; ++i)
            if (a[i] > tb) cand[o++] = a[i];
        __syncthreads();

        // ---- per-wave: all candidates in registers (4 slots/lane), barrier-free
        uint32_t r0 = (lane        < (int)C) ? cand[lane      ] : 0u;
        uint32_t r1 = (lane + 64   < (int)C) ? cand[lane +  64] : 0u;
        uint32_t r2 = (lane + 128  < (int)C) ? cand[lane + 128] : 0u;
        uint32_t r3 = (lane + 192  < (int)C) ? cand[lane + 192] : 0u;

        uint32_t mx = max(max(r0, r1), max(r2, r3));
#pragma unroll
        for (int off = 32; off >= 1; off >>= 1)
            mx = max(mx, (uint32_t)__shfl_xor(mx, off, 64));

        // smallest m with count(a > m) < 65  ==  65th-largest bit pattern.
        // Every element > mid (mid >= tb) is a candidate, so counting candidates
        // is exact. Ties handled by the strict-greater counting rule.
        uint32_t lo = tb + 1u, hi = mx;
        while (lo < hi) {
            uint32_t mid = lo + ((hi - lo) >> 1);
            uint32_t c = ((r0 > mid) ? 1u : 0u) + ((r1 > mid) ? 1u : 0u) +
                         ((r2 > mid) ? 1u : 0u) + ((r3 > mid) ? 1u : 0u);
#pragma unroll
            for (int off = 32; off >= 1; off >>= 1) c += __shfl_xor(c, off, 64);
            if (c < 65u) hi = mid; else lo = mid + 1u;
        }
        b65 = lo;
    } else {
        // ---- exact fallback: block-wide bit-pattern bisection over full row
        uint32_t lo = 0u, hi = 0x7F800000u;
        while (lo < hi) {
            uint32_t mid = lo + ((hi - lo) >> 1);
            uint32_t c = 0;
#pragma unroll
            for (int i = 0; i < EPT; ++i) c += (a[i] > mid) ? 1u : 0u;
#pragma unroll
            for (int off = 32; off >= 1; off >>= 1) c += __shfl_xor(c, off, 64);
            __syncthreads();
            if (lane == 0) wsum[wave] = c;
            __syncthreads();
            uint32_t tot = wsum[0] + wsum[1] + wsum[2] + wsum[3];
            if (tot < 65u) hi = mid; else lo = mid + 1u;
        }
        b65 = lo;
    }

    // ---- v64 = min of elements strictly greater than b65 (iff exactly 64 exist)
    uint32_t cnt = 0, mn = 0xFFFFFFFFu;
#pragma unroll
    for (int i = 0; i < EPT; ++i) {
        bool g = a[i] > b65;
        cnt += g ? 1u : 0u;
        mn = min(mn, g ? a[i] : 0xFFFFFFFFu);
    }
#pragma unroll
    for (int off = 32; off >= 1; off >>= 1) {
        cnt += __shfl_xor(cnt, off, 64);
        mn = min(mn, (uint32_t)__shfl_xor(mn, off, 64));
    }
    __syncthreads();                     // protect wsum/fsum prior use
    if (lane == 0) { wsum[wave] = cnt; fsum[wave] = __uint_as_float(mn); }
    __syncthreads();
    const uint32_t Ct = wsum[0] + wsum[1] + wsum[2] + wsum[3];
    const uint32_t M  = min(min(__float_as_uint(fsum[0]), __float_as_uint(fsum[1])),
                            min(__float_as_uint(fsum[2]), __float_as_uint(fsum[3])));
    const float v65 = __uint_as_float(b65);
    const float v64 = (Ct == 64u) ? __uint_as_float(M) : v65;
    const float Q = fmaf(0.015625f, v64 - v65, v65);

    // ---- soft-threshold + coalesced store
#pragma unroll
    for (int i = 0; i < 4; ++i) {
        float r[4];
#pragma unroll
        for (int j = 0; j < 4; ++j) {
            const int idx = 4*i + j;
            float mag = fmaxf(__uint_as_float(a[idx]) - Q, 0.0f);
            uint32_t bits = __float_as_uint(mag) | (((sbits >> idx) & 1u) << 31);
            r[j] = __uint_as_float(bits);
        }
        o4[t + THREADS * i] = make_float4(r[0], r[1], r[2], r[3]);
    }
}

extern "C" void kernel_launch(void* const* d_in, const int* in_sizes, int n_in,
                              void* d_out, int out_size, void* d_ws, size_t ws_size,
                              hipStream_t stream) {
    const float* X   = (const float*)d_in[0];
    float*       out = (float*)d_out;
    const int rows = in_sizes[0] / NCOLS;   // 16384
    topk_sparsify<<<rows, THREADS, 0, stream>>>(X, out);
}

// Round 4
// 441.889 us; speedup vs baseline: 1.0117x; 1.0117x over previous
//
#include <hip/hip_runtime.h>
#include <cstdint>

constexpr int NCOLS   = 4096;
constexpr int THREADS = 256;
constexpr int EPT     = 16;     // elements per thread
constexpr int CAP     = 256;    // max candidates (4 per lane per wave)

typedef float floatx4 __attribute__((ext_vector_type(4)));

__device__ __forceinline__ uint32_t mbcnt64(uint64_t m) {
    uint32_t c = __builtin_amdgcn_mbcnt_lo((uint32_t)m, 0u);
    return __builtin_amdgcn_mbcnt_hi((uint32_t)(m >> 32), c);
}

__global__ __launch_bounds__(THREADS) void topk_sparsify(
    const float* __restrict__ X, float* __restrict__ out)
{
    const int row  = blockIdx.x;
    const int t    = threadIdx.x;
    const int wave = t >> 6;
    const int lane = t & 63;

    __shared__ uint32_t wsum[4];
    __shared__ float    fsum[4];
    __shared__ uint32_t wmn[4];
    __shared__ uint32_t cand[CAP];

    const floatx4* __restrict__ x4 =
        reinterpret_cast<const floatx4*>(X + (size_t)row * NCOLS);
    floatx4* __restrict__ o4 = reinterpret_cast<floatx4*>(out + (size_t)row * NCOLS);

    // ---- load row; |x| bit patterns + packed signs; accumulate sum(x^2)
    uint32_t a[EPT];
    uint32_t sbits = 0;
    float ss = 0.0f;
#pragma unroll
    for (int i = 0; i < 4; ++i) {
        floatx4 v = x4[t + THREADS * i];
        uint32_t u0 = __float_as_uint(v.x), u1 = __float_as_uint(v.y);
        uint32_t u2 = __float_as_uint(v.z), u3 = __float_as_uint(v.w);
        a[4*i+0] = u0 & 0x7FFFFFFFu;  a[4*i+1] = u1 & 0x7FFFFFFFu;
        a[4*i+2] = u2 & 0x7FFFFFFFu;  a[4*i+3] = u3 & 0x7FFFFFFFu;
        sbits |= (u0 >> 31) << (4*i+0);
        sbits |= (u1 >> 31) << (4*i+1);
        sbits |= (u2 >> 31) << (4*i+2);
        sbits |= (u3 >> 31) << (4*i+3);
        ss = fmaf(v.x, v.x, ss); ss = fmaf(v.y, v.y, ss);
        ss = fmaf(v.z, v.z, ss); ss = fmaf(v.w, v.w, ss);
    }

    // ---- sigma (block reduce of sum of squares; the one float reduction)
#pragma unroll
    for (int off = 32; off >= 1; off >>= 1) ss += __shfl_xor(ss, off, 64);
    if (lane == 0) fsum[wave] = ss;
    __syncthreads();
    const float sigma = sqrtf(fsum[0] + fsum[1] + fsum[2] + fsum[3]) * (1.0f / 64.0f);

    // ---- find T with 65 <= C <= CAP (ballot counting; typically 1 iteration)
    float T = 2.12f * sigma;
    uint32_t tb = 0, C = 0;
    bool ok = false;
    for (int it = 0; it < 12; ++it) {
        tb = __float_as_uint(T);
        uint32_t cw = 0;
#pragma unroll
        for (int i = 0; i < EPT; ++i)
            cw += (uint32_t)__popcll(__ballot(a[i] > tb));
        if (lane == 0) wsum[wave] = cw;
        __syncthreads();
        C = wsum[0] + wsum[1] + wsum[2] + wsum[3];
        if (C >= 65u && C <= (uint32_t)CAP) { ok = true; break; }
        __syncthreads();                 // all reads done before rewrite
        T = (C < 65u) ? T * 0.82f : T * 1.25f;
    }

    uint32_t b65, Ct, M;
    if (ok) {
        // ---- gather candidates via mbcnt(ballot) offsets (no scans, no atomics)
        uint32_t base = 0;
#pragma unroll
        for (int w = 0; w < 4; ++w) base += (w < wave) ? wsum[w] : 0u;
#pragma unroll
        for (int i = 0; i < EPT; ++i) {
            uint64_t m = __ballot(a[i] > tb);
            if (a[i] > tb) cand[base + mbcnt64(m)] = a[i];
            base += (uint32_t)__popcll(m);
        }
        __syncthreads();

        // ---- each wave holds all candidates in 4 regs/lane
        uint32_t r0 = (lane       < (int)C) ? cand[lane      ] : 0u;
        uint32_t r1 = (lane + 64  < (int)C) ? cand[lane +  64] : 0u;
        uint32_t r2 = (lane + 128 < (int)C) ? cand[lane + 128] : 0u;
        uint32_t r3 = (lane + 192 < (int)C) ? cand[lane + 192] : 0u;

        // smallest m with count(> m) < 65 == 65th-largest bit pattern.
        // Wave-uniform scalar bisection; counts via ballot+popcount.
        uint32_t lo = tb + 1u, hi = 0x7F800000u;
        while (lo < hi) {
            uint32_t mid = lo + ((hi - lo) >> 1);
            uint32_t c = (uint32_t)(__popcll(__ballot(r0 > mid)) +
                                    __popcll(__ballot(r1 > mid)) +
                                    __popcll(__ballot(r2 > mid)) +
                                    __popcll(__ballot(r3 > mid)));
            if (c < 65u) hi = mid; else lo = mid + 1u;
        }
        b65 = lo;

        // ---- v64 inputs from candidates (wave-local, barrier-free; exact:
        // every element > b65 is > tb, hence a candidate)
        Ct = (uint32_t)(__popcll(__ballot(r0 > b65)) +
                        __popcll(__ballot(r1 > b65)) +
                        __popcll(__ballot(r2 > b65)) +
                        __popcll(__ballot(r3 > b65)));
        uint32_t mn = 0xFFFFFFFFu;
        mn = min(mn, (r0 > b65) ? r0 : 0xFFFFFFFFu);
        mn = min(mn, (r1 > b65) ? r1 : 0xFFFFFFFFu);
        mn = min(mn, (r2 > b65) ? r2 : 0xFFFFFFFFu);
        mn = min(mn, (r3 > b65) ? r3 : 0xFFFFFFFFu);
#pragma unroll
        for (int off = 32; off >= 1; off >>= 1)
            mn = min(mn, (uint32_t)__shfl_xor(mn, off, 64));
        M = mn;
    } else {
        // ---- exact fallback: block-wide bit-pattern bisection over full row
        uint32_t lo = 0u, hi = 0x7F800000u;
        while (lo < hi) {
            uint32_t mid = lo + ((hi - lo) >> 1);
            uint32_t cw = 0;
#pragma unroll
            for (int i = 0; i < EPT; ++i)
                cw += (uint32_t)__popcll(__ballot(a[i] > mid));
            if (lane == 0) wsum[wave] = cw;
            __syncthreads();
            uint32_t tot = wsum[0] + wsum[1] + wsum[2] + wsum[3];
            __syncthreads();
            if (tot < 65u) hi = mid; else lo = mid + 1u;
        }
        b65 = lo;

        // block-wide count + min of elements strictly > b65
        uint32_t cw = 0, mn = 0xFFFFFFFFu;
#pragma unroll
        for (int i = 0; i < EPT; ++i) {
            cw += (uint32_t)__popcll(__ballot(a[i] > b65));
            mn = min(mn, (a[i] > b65) ? a[i] : 0xFFFFFFFFu);
        }
#pragma unroll
        for (int off = 32; off >= 1; off >>= 1)
            mn = min(mn, (uint32_t)__shfl_xor(mn, off, 64));
        if (lane == 0) { wsum[wave] = cw; wmn[wave] = mn; }
        __syncthreads();
        Ct = wsum[0] + wsum[1] + wsum[2] + wsum[3];
        M  = min(min(wmn[0], wmn[1]), min(wmn[2], wmn[3]));
    }

    const float v65 = __uint_as_float(b65);
    const float v64 = (Ct == 64u) ? __uint_as_float(M) : v65;
    const float Q = fmaf(0.015625f, v64 - v65, v65);   // frac exact in binary

    // ---- soft-threshold + coalesced nontemporal store
#pragma unroll
    for (int i = 0; i < 4; ++i) {
        floatx4 f;
#pragma unroll
        for (int j = 0; j < 4; ++j) {
            const int idx = 4*i + j;
            float mag = fmaxf(__uint_as_float(a[idx]) - Q, 0.0f);
            uint32_t bits = __float_as_uint(mag) | (((sbits >> idx) & 1u) << 31);
            f[j] = __uint_as_float(bits);
        }
        __builtin_nontemporal_store(f, &o4[t + THREADS * i]);
    }
}

extern "C" void kernel_launch(void* const* d_in, const int* in_sizes, int n_in,
                              void* d_out, int out_size, void* d_ws, size_t ws_size,
                              hipStream_t stream) {
    const float* X   = (const float*)d_in[0];
    float*       out = (float*)d_out;
    const int rows = in_sizes[0] / NCOLS;   // 16384
    topk_sparsify<<<rows, THREADS, 0, stream>>>(X, out);
}